// Round 7
// baseline (61.576 us; speedup 1.0000x reference)
//
#include <hip/hip_runtime.h>
#include <math.h>

// ---------------------------------------------------------------------------
// ZBL repulsion, R7: LDS-resident atom table (kill the TA/TCP random gather).
//  - z8 (u8 atomic numbers, 100 KB) copied into LDS once per block;
//    per-pair "gather" becomes ds_read_u8 (bank-based, ~2-3-way = cheap)
//  - za via 128-entry LDS float table; cp = zi*zj exact
//  - persistent blocks: 1 block/CU (125 KB LDS), contiguous 25k-pair chunk,
//    double-buffered disp staging + next-tile reg prefetch (T14 split:
//    issue loads at iter top, ds_write after compute)
//  - native exp2/rcp/rsq lean math; wave segmented scan on sorted idx_i
// ---------------------------------------------------------------------------

#define LOG2E 1.4426950408889634f
#define BLK   1024
#define TILE  1024
#define NBLK  256

static __device__ __forceinline__ float rcpf_(float x)  { return __builtin_amdgcn_rcpf(x); }
static __device__ __forceinline__ float rsqf_(float x)  { return __builtin_amdgcn_rsqf(x); }
static __device__ __forceinline__ float exp2f_(float x) { return __builtin_amdgcn_exp2f(x); }
static __device__ __forceinline__ float log2f_(float x) { return __builtin_amdgcn_logf(x); }

__global__ void zbl_build_z8(const float* __restrict__ an,
                             unsigned char* __restrict__ z8, int n) {
    int i = blockIdx.x * blockDim.x + threadIdx.x;
    if (i >= n) return;
    int z = (int)(an[i] + 0.5f);
    z8[i] = (unsigned char)min(max(z, 1), 127);
}

__global__ __launch_bounds__(BLK) void zbl_pair_kernel(
    const float* __restrict__ disp,        // [P*3]
    const int*   __restrict__ idx_i,       // sorted
    const int*   __restrict__ idx_j,
    const float* __restrict__ batch_mask,  // [P]
    const unsigned char* __restrict__ z8g, // [N] atomic number as u8
    const float* __restrict__ a_coef_ptr,
    const float* __restrict__ a_exp_ptr,
    const float* __restrict__ phi_c,
    const float* __restrict__ phi_e,
    float* __restrict__ out_acc,           // [N] pre-zeroed accumulator
    int nA, int nP)
{
    extern __shared__ unsigned char smem[];
    const int nA_pad = (nA + 15) & ~15;
    unsigned char* s_z8  = smem;                              // nA_pad bytes
    float*         s_za  = (float*)(smem + nA_pad);           // 128 floats
    float*         s_dsp = (float*)(smem + nA_pad + 512);     // 2 * TILE*3 floats

    const int tid = threadIdx.x;

    // ---- copy z8 table to LDS (coalesced uint4), build za table
    {
        const int nw = nA >> 4;
        const uint4* g4 = reinterpret_cast<const uint4*>(z8g);
        uint4* s4 = reinterpret_cast<uint4*>(s_z8);
        for (int i = tid; i < nw; i += BLK) s4[i] = g4[i];
        for (int i = (nw << 4) + tid; i < nA; i += BLK) s_z8[i] = z8g[i];
    }
    if (tid < 128) {
        float ae = fabsf(a_exp_ptr[0]);
        int z = (tid < 1) ? 1 : tid;
        s_za[tid] = exp2f_(ae * log2f_((float)z));   // z^|ae|, finite for z<=127
    }

    // per-thread uniforms
    const float ac_inv = rcpf_(fmaxf(fabsf(a_coef_ptr[0]), 1e-10f));
    float c0 = fabsf(phi_c[0]), c1 = fabsf(phi_c[1]);
    float c2 = fabsf(phi_c[2]), c3 = fabsf(phi_c[3]);
    const float cinv = rcpf_(fmaxf(c0 + c1 + c2 + c3, 1e-10f));
    c0 *= cinv; c1 *= cinv; c2 *= cinv; c3 *= cinv;
    const float e0 = fmaxf(fabsf(phi_e[0]), 1e-10f);
    const float e1 = fmaxf(fabsf(phi_e[1]), 1e-10f);
    const float e2 = fmaxf(fabsf(phi_e[2]), 1e-10f);
    const float e3 = fmaxf(fabsf(phi_e[3]), 1e-10f);

    const int chunk = (nP + gridDim.x - 1) / gridDim.x;
    const int cbeg  = blockIdx.x * chunk;
    const int cend  = min(cbeg + chunk, nP);
    const int ntiles = (cbeg < cend) ? ((cend - cbeg + TILE - 1) / TILE) : 0;
    const int lane = tid & 63;

    // ---- prologue: stage tile 0 disp (reg->LDS buf0) + tile 0 idx/bm
    float4 pf = make_float4(0, 0, 0, 0);
    int   cur_ii = -1, cur_jj = 0;
    float cur_bm = 0.0f;
    if (ntiles > 0) {
        const int  pbeg = cbeg;
        const int  nfl  = min(TILE, cend - pbeg) * 3;
        const long fb   = (long)pbeg * 3;
        if (tid * 4 + 3 < nfl) {
            pf = *reinterpret_cast<const float4*>(disp + fb + tid * 4);
        } else {
            float tmp[4] = {0, 0, 0, 0};
            for (int k = 0; k < 4; ++k)
                if (tid * 4 + k < nfl) tmp[k] = disp[fb + tid * 4 + k];
            pf = make_float4(tmp[0], tmp[1], tmp[2], tmp[3]);
        }
        if (tid * 4 < nfl)
            reinterpret_cast<float4*>(s_dsp)[tid] = pf;
        const int p = cbeg + tid;
        if (p < cend) {
            cur_ii = idx_i[p];
            cur_jj = idx_j[p];
            cur_bm = batch_mask[p];
        }
    }
    __syncthreads();

    for (int t = 0; t < ntiles; ++t) {
        const int  buf      = t & 1;
        const bool hasNext  = (t + 1 < ntiles);
        int   nii = -1, njj = 0;
        float nbm = 0.0f;

        // A) prefetch next tile into registers (in flight during compute)
        if (hasNext) {
            const int  pbeg = cbeg + (t + 1) * TILE;
            const int  nfl  = min(TILE, cend - pbeg) * 3;
            const long fb   = (long)pbeg * 3;
            if (tid * 4 + 3 < nfl) {
                pf = *reinterpret_cast<const float4*>(disp + fb + tid * 4);
            } else {
                float tmp[4] = {0, 0, 0, 0};
                for (int k = 0; k < 4; ++k)
                    if (tid * 4 + k < nfl) tmp[k] = disp[fb + tid * 4 + k];
                pf = make_float4(tmp[0], tmp[1], tmp[2], tmp[3]);
            }
            const int p = pbeg + tid;
            if (p < cend) {
                nii = idx_i[p];
                njj = idx_j[p];
                nbm = batch_mask[p];
            }
        }

        // B) compute tile t
        float rep = 0.0f;
        int   key = -1;
        if (cur_ii >= 0) {
            const int zi = (int)s_z8[cur_ii];
            const int zj = (int)s_z8[cur_jj];
            const float za_i = s_za[zi];
            const float za_j = s_za[zj];
            const float* sd = s_dsp + buf * (TILE * 3) + tid * 3;
            const float add = 1.0f - cur_bm;
            const float dx = sd[0] + add;
            const float dy = sd[1] + add;
            const float dz = sd[2] + add;

            float d2   = fmaxf(dx * dx + dy * dy + dz * dz, 1e-20f);
            float rsq  = rsqf_(d2);
            float dist = d2 * rsq;                  // sqrt(d2); 1/dist == rsq

            float tt = dist * 0.1f;
            float tc = fminf(fmaxf(tt, 1e-9f), 1.0f - 1e-9f);
            float u  = (1.0f - 2.0f * tc) * rcpf_(tc - tc * tc);
            float s  = rcpf_(1.0f + exp2f_(u * LOG2E));
            float sw = (tt >= 1.0f) ? 1.0f : s;

            float za_sum = za_i + za_j;
            float arg  = fminf(dist * za_sum * ac_inv, 1e6f);
            float narg = -arg * LOG2E;
            float phi  = c0 * exp2f_(e0 * narg) + c1 * exp2f_(e1 * narg) +
                         c2 * exp2f_(e2 * narg) + c3 * exp2f_(e3 * narg);
            phi = fminf(fmaxf(phi, 1e-30f), 1e6f);

            float cp   = fminf((float)(zi * zj), 1e4f);
            float brep = fminf(0.5f * cp * rsq, 1e6f);
            float r    = brep * phi * fmaxf(sw, 1e-30f);
            r = fminf(fmaxf(r, 0.0f), 1e6f);
            if (!(r == r)) r = 0.0f;
            rep = r * cur_bm;
            key = cur_ii;
        }

        // C) wave-level reduction on sorted keys
        {
            const int k0 = __shfl(key, 0);
            if (__all(key == k0)) {
                float v = rep;
                #pragma unroll
                for (int d = 1; d < 64; d <<= 1) v += __shfl_xor(v, d);
                if (lane == 0 && k0 >= 0) atomicAdd(&out_acc[k0], v);
            } else {
                float v = rep;
                int   k = key;
                #pragma unroll
                for (int d = 1; d < 64; d <<= 1) {
                    float nv = __shfl_down(v, d);
                    int   nk = __shfl_down(k, d);
                    if (lane + d < 64 && nk == k) v += nv;
                }
                int pk = __shfl_up(k, 1);
                bool head = (lane == 0) || (pk != k);
                if (head && k >= 0) atomicAdd(&out_acc[k], v);
            }
        }

        // D) write prefetched disp into the other buffer (loads have had
        //    all of B+C to land), then E) barrier
        if (hasNext) {
            const int nfl = min(TILE, cend - (cbeg + (t + 1) * TILE)) * 3;
            if (tid * 4 < nfl)
                reinterpret_cast<float4*>(s_dsp + (buf ^ 1) * (TILE * 3))[tid] = pf;
        }
        __syncthreads();

        cur_ii = nii; cur_jj = njj; cur_bm = nbm;
    }
}

__global__ void zbl_epilogue(float* __restrict__ out,
                             const float* __restrict__ atom_mask, int n) {
    int i = blockIdx.x * blockDim.x + threadIdx.x;
    if (i >= n) return;
    float v = out[i] * atom_mask[i];
    v = fminf(fmaxf(v, 0.0f), 1e6f);
    if (!(v == v)) v = 0.0f;
    out[i] = v * 0.01f;
}

extern "C" void kernel_launch(void* const* d_in, const int* in_sizes, int n_in,
                              void* d_out, int out_size, void* d_ws, size_t ws_size,
                              hipStream_t stream) {
    const float* an         = (const float*)d_in[0];
    const float* disp       = (const float*)d_in[1];
    const int*   idx_i      = (const int*)d_in[2];
    const int*   idx_j      = (const int*)d_in[3];
    const float* atom_mask  = (const float*)d_in[4];
    const float* batch_mask = (const float*)d_in[5];
    const float* a_coef     = (const float*)d_in[8];
    const float* a_exp      = (const float*)d_in[9];
    const float* phi_c      = (const float*)d_in[10];
    const float* phi_e      = (const float*)d_in[11];

    const int nA = in_sizes[0];
    const int nP = in_sizes[2];
    float* out = (float*)d_out;

    hipMemsetAsync(d_out, 0, (size_t)out_size * sizeof(float), stream);

    unsigned char* z8 = (unsigned char*)d_ws;   // 100 KB, ws ample

    zbl_build_z8<<<(nA + 255) / 256, 256, 0, stream>>>(an, z8, nA);

    const int nA_pad = (nA + 15) & ~15;
    const size_t smem = (size_t)nA_pad + 512 + 2 * TILE * 3 * sizeof(float);
    zbl_pair_kernel<<<NBLK, BLK, smem, stream>>>(
        disp, idx_i, idx_j, batch_mask, z8, a_coef, a_exp, phi_c, phi_e,
        out, nA, nP);

    zbl_epilogue<<<(nA + 255) / 256, 256, 0, stream>>>(out, atom_mask, nA);
}

// Round 8
// 47.396 us; speedup vs baseline: 1.2992x; 1.2992x over previous
//
#include <hip/hip_runtime.h>
#include <math.h>

// ---------------------------------------------------------------------------
// ZBL repulsion, R8: LDS atom table + barrier-free register-pipelined streams.
//  - z8 (u8 Z, 100 KB) + za[256] table in LDS, loaded once per block
//    (kills ALL random global gather line-misses -> stream misses only)
//  - grid-stride loop, depth-2 register pipeline: issue next iter's loads
//    (idx_i, idx_j, bm, float3 disp) at loop top, compute current, NO
//    barriers / NO LDS staging in the loop (each thread owns its 12 B disp)
//  - build kernel also zeroes d_out (memset dispatch dropped)
//  - native exp2/rcp/rsq lean math; wave reduce: butterfly fast path when
//    wave-uniform key, segmented scan otherwise; sorted idx_i
// ---------------------------------------------------------------------------

#define LOG2E 1.4426950408889634f
#define BLK   1024
#define NBLK  256

static __device__ __forceinline__ float rcpf_(float x)  { return __builtin_amdgcn_rcpf(x); }
static __device__ __forceinline__ float rsqf_(float x)  { return __builtin_amdgcn_rsqf(x); }
static __device__ __forceinline__ float exp2f_(float x) { return __builtin_amdgcn_exp2f(x); }
static __device__ __forceinline__ float log2f_(float x) { return __builtin_amdgcn_logf(x); }

struct f3 { float x, y, z; };

__global__ void zbl_build_z8(const float* __restrict__ an,
                             unsigned char* __restrict__ z8,
                             float* __restrict__ out, int n) {
    int i = blockIdx.x * blockDim.x + threadIdx.x;
    if (i >= n) return;
    int z = (int)(an[i] + 0.5f);
    z8[i] = (unsigned char)min(max(z, 1), 255);
    out[i] = 0.0f;                       // fold d_out zeroing into this pass
}

__global__ __launch_bounds__(BLK) void zbl_pair_kernel(
    const float* __restrict__ disp,        // [P*3]
    const int*   __restrict__ idx_i,       // sorted
    const int*   __restrict__ idx_j,
    const float* __restrict__ batch_mask,  // [P]
    const unsigned char* __restrict__ z8g, // [N] Z as u8
    const float* __restrict__ a_coef_ptr,
    const float* __restrict__ a_exp_ptr,
    const float* __restrict__ phi_c,
    const float* __restrict__ phi_e,
    float* __restrict__ out_acc,           // [N] zeroed accumulator
    int nA, int nP)
{
    extern __shared__ unsigned char smem[];
    const int nA_pad = (nA + 15) & ~15;
    unsigned char* s_z8 = smem;                     // nA_pad bytes
    float*         s_za = (float*)(smem + nA_pad);  // 256 floats

    const int tid = threadIdx.x;

    // ---- one-time: copy z8 table (coalesced uint4) + build za table
    {
        const int nw = nA >> 4;
        const uint4* g4 = reinterpret_cast<const uint4*>(z8g);
        uint4* s4 = reinterpret_cast<uint4*>(s_z8);
        for (int i = tid; i < nw; i += BLK) s4[i] = g4[i];
        for (int i = (nw << 4) + tid; i < nA; i += BLK) s_z8[i] = z8g[i];
    }
    if (tid < 256) {
        float ae = fabsf(a_exp_ptr[0]);
        int z = max(tid, 1);
        s_za[tid] = exp2f_(ae * log2f_((float)z));   // z^|ae|
    }
    __syncthreads();                                  // the only barrier

    // per-thread uniforms
    const float ac_inv = rcpf_(fmaxf(fabsf(a_coef_ptr[0]), 1e-10f));
    float c0 = fabsf(phi_c[0]), c1 = fabsf(phi_c[1]);
    float c2 = fabsf(phi_c[2]), c3 = fabsf(phi_c[3]);
    const float cinv = rcpf_(fmaxf(c0 + c1 + c2 + c3, 1e-10f));
    c0 *= cinv; c1 *= cinv; c2 *= cinv; c3 *= cinv;
    const float e0 = fmaxf(fabsf(phi_e[0]), 1e-10f);
    const float e1 = fmaxf(fabsf(phi_e[1]), 1e-10f);
    const float e2 = fmaxf(fabsf(phi_e[2]), 1e-10f);
    const float e3 = fmaxf(fabsf(phi_e[3]), 1e-10f);

    const int chunk = (nP + (int)gridDim.x - 1) / (int)gridDim.x;
    const int cbeg  = blockIdx.x * chunk;
    const int cend  = min(cbeg + chunk, nP);
    const int lane  = tid & 63;

    // ---- prologue: load iteration 0 into registers
    int   cii = -1, cjj = 0;
    float cbm = 0.0f, cdx = 0.0f, cdy = 0.0f, cdz = 0.0f;
    {
        const int p = cbeg + tid;
        if (p < cend) {
            cii = idx_i[p];
            cjj = idx_j[p];
            cbm = batch_mask[p];
            f3 d = *reinterpret_cast<const f3*>(disp + (long)p * 3);
            cdx = d.x; cdy = d.y; cdz = d.z;
        }
    }

    for (int pb = cbeg; pb < cend; pb += BLK) {
        // A) issue next iteration's loads (full iteration of latency to hide)
        int   nii = -1, njj = 0;
        float nbm = 0.0f, ndx = 0.0f, ndy = 0.0f, ndz = 0.0f;
        {
            const int p = pb + BLK + tid;
            if (p < cend) {
                nii = idx_i[p];
                njj = idx_j[p];
                nbm = batch_mask[p];
                f3 d = *reinterpret_cast<const f3*>(disp + (long)p * 3);
                ndx = d.x; ndy = d.y; ndz = d.z;
            }
        }

        // B) compute current iteration from registers + LDS tables
        float rep = 0.0f;
        int   key = -1;
        if (cii >= 0) {
            const int zi = (int)s_z8[cii];
            const int zj = (int)s_z8[cjj];
            const float za_i = s_za[zi];
            const float za_j = s_za[zj];

            const float add = 1.0f - cbm;
            const float dx = cdx + add, dy = cdy + add, dz = cdz + add;

            float d2   = fmaxf(dx * dx + dy * dy + dz * dz, 1e-20f);
            float rsq  = rsqf_(d2);
            float dist = d2 * rsq;                  // sqrt(d2); 1/dist == rsq

            float tt = dist * 0.1f;
            float tc = fminf(fmaxf(tt, 1e-9f), 1.0f - 1e-9f);
            float u  = (1.0f - 2.0f * tc) * rcpf_(tc - tc * tc);
            float s  = rcpf_(1.0f + exp2f_(u * LOG2E));
            float sw = (tt >= 1.0f) ? 1.0f : s;

            float za_sum = za_i + za_j;
            float arg  = fminf(dist * za_sum * ac_inv, 1e6f);
            float narg = -arg * LOG2E;
            float phi  = c0 * exp2f_(e0 * narg) + c1 * exp2f_(e1 * narg) +
                         c2 * exp2f_(e2 * narg) + c3 * exp2f_(e3 * narg);
            phi = fminf(fmaxf(phi, 1e-30f), 1e6f);

            float cp   = fminf((float)(zi * zj), 1e4f);
            float brep = fminf(0.5f * cp * rsq, 1e6f);
            float r    = brep * phi * fmaxf(sw, 1e-30f);
            r = fminf(fmaxf(r, 0.0f), 1e6f);
            if (!(r == r)) r = 0.0f;
            rep = r * cbm;
            key = cii;
        }

        // C) wave-level reduction on sorted keys
        {
            const int k0 = __shfl(key, 0);
            if (__all(key == k0)) {
                float v = rep;
                #pragma unroll
                for (int d = 1; d < 64; d <<= 1) v += __shfl_xor(v, d);
                if (lane == 0 && k0 >= 0) atomicAdd(&out_acc[k0], v);
            } else {
                float v = rep;
                int   k = key;
                #pragma unroll
                for (int d = 1; d < 64; d <<= 1) {
                    float nv = __shfl_down(v, d);
                    int   nk = __shfl_down(k, d);
                    if (lane + d < 64 && nk == k) v += nv;
                }
                int pk = __shfl_up(k, 1);
                bool head = (lane == 0) || (pk != k);
                if (head && k >= 0) atomicAdd(&out_acc[k], v);
            }
        }

        // D) rotate pipeline registers
        cii = nii; cjj = njj; cbm = nbm;
        cdx = ndx; cdy = ndy; cdz = ndz;
    }
}

__global__ void zbl_epilogue(float* __restrict__ out,
                             const float* __restrict__ atom_mask, int n) {
    int i = blockIdx.x * blockDim.x + threadIdx.x;
    if (i >= n) return;
    float v = out[i] * atom_mask[i];
    v = fminf(fmaxf(v, 0.0f), 1e6f);
    if (!(v == v)) v = 0.0f;
    out[i] = v * 0.01f;
}

extern "C" void kernel_launch(void* const* d_in, const int* in_sizes, int n_in,
                              void* d_out, int out_size, void* d_ws, size_t ws_size,
                              hipStream_t stream) {
    const float* an         = (const float*)d_in[0];
    const float* disp       = (const float*)d_in[1];
    const int*   idx_i      = (const int*)d_in[2];
    const int*   idx_j      = (const int*)d_in[3];
    const float* atom_mask  = (const float*)d_in[4];
    const float* batch_mask = (const float*)d_in[5];
    const float* a_coef     = (const float*)d_in[8];
    const float* a_exp      = (const float*)d_in[9];
    const float* phi_c      = (const float*)d_in[10];
    const float* phi_e      = (const float*)d_in[11];

    const int nA = in_sizes[0];
    const int nP = in_sizes[2];
    float* out = (float*)d_out;

    unsigned char* z8 = (unsigned char*)d_ws;   // 100 KB, ws ample

    // pass 1: build z8 AND zero d_out (no separate memset dispatch)
    zbl_build_z8<<<(nA + 255) / 256, 256, 0, stream>>>(an, z8, out, nA);

    const int nA_pad = (nA + 15) & ~15;
    const size_t smem = (size_t)nA_pad + 256 * sizeof(float);
    zbl_pair_kernel<<<NBLK, BLK, smem, stream>>>(
        disp, idx_i, idx_j, batch_mask, z8, a_coef, a_exp, phi_c, phi_e,
        out, nA, nP);

    zbl_epilogue<<<(nA + 255) / 256, 256, 0, stream>>>(out, atom_mask, nA);
}